// Round 2
// baseline (6996.249 us; speedup 1.0000x reference)
//
#include <hip/hip_runtime.h>

// ---------------- constants ----------------
#define SQL 2048      // sequence length
#define DIM 512
#define NHEADS 8
#define HD 64         // head dim
#define NLAYERS 4
#define NLEVELS 3
#define HID 2048
#define VOC 50257
#define CHUNK 64
#define NCHUNK 32     // SQL / CHUNK
#define SD (SQL * DIM)

__device__ __forceinline__ float gelu_f(float x) {
    float x3 = x * x * x;
    return 0.5f * x * (1.f + tanhf(0.7978845608028654f * (x + 0.044715f * x3)));
}

// fmap = elu(x)+1 : x>0 ? x+1 : exp(x)
__device__ __forceinline__ float fmap_f(float x) {
    return x > 0.f ? x + 1.f : expf(x);
}

// ---------------- embedding ----------------
__global__ __launch_bounds__(256) void embed_k(
    const float* __restrict__ tok, const float* __restrict__ pos,
    const int* __restrict__ ids, float* __restrict__ x)
{
    int idx = blockIdx.x * 256 + threadIdx.x;       // 0 .. S*D-1
    int t = idx >> 9;                               // idx / 512
    int d = idx & 511;
    x[idx] = tok[(size_t)ids[t] * DIM + d] + pos[idx];
}

// ---------------- layernorm (one block per token) ----------------
__global__ __launch_bounds__(256) void ln_k(
    const float* __restrict__ in, float* __restrict__ out,
    const float* __restrict__ w, const float* __restrict__ b)
{
    int t = blockIdx.x, tid = threadIdx.x;
    float v0 = in[t * DIM + tid];
    float v1 = in[t * DIM + 256 + tid];
    float s = v0 + v1, sq = v0 * v0 + v1 * v1;
    #pragma unroll
    for (int off = 32; off > 0; off >>= 1) {
        s  += __shfl_down(s, off);
        sq += __shfl_down(sq, off);
    }
    __shared__ float ss[4], sqs[4];
    int wave = tid >> 6, lane = tid & 63;
    if (lane == 0) { ss[wave] = s; sqs[wave] = sq; }
    __syncthreads();
    float S  = ss[0] + ss[1] + ss[2] + ss[3];
    float SQ = sqs[0] + sqs[1] + sqs[2] + sqs[3];
    float m   = S * (1.f / DIM);
    float var = SQ * (1.f / DIM) - m * m;
    float rs  = rsqrtf(var + 1e-5f);
    out[t * DIM + tid]       = (v0 - m) * rs * w[tid]       + b[tid];
    out[t * DIM + 256 + tid] = (v1 - m) * rs * w[256 + tid] + b[256 + tid];
}

// ---------------- generic GEMM ----------------
// C(MxN) = act(A(MxK) @ B + bias) [+ Rsrc]   all f32
// BT=false: B is KxN.  BT=true: B is NxK (head: logits = x @ tok^T).
// ACT: 0 none, 1 fmap, 2 gelu.
#define BM 64
#define BN 64
#define BK 16

template<int ACT, bool BT, bool RES>
__global__ __launch_bounds__(256) void gemm_k(
    const float* __restrict__ A, const float* __restrict__ B,
    const float* __restrict__ bias, const float* __restrict__ Rsrc,
    float* __restrict__ C,
    int M, int N, int K)
{
    __shared__ float As[BM][BK + 1];
    __shared__ float Bs[BK][BN + 1];

    const int tid = threadIdx.x;
    const int tx = tid & 15, ty = tid >> 4;
    const int m0 = blockIdx.y * BM, n0 = blockIdx.x * BN;

    const int a_r = tid >> 2;            // 0..63
    const int a_k = (tid & 3) << 2;      // 0,4,8,12

    float acc[4][4] = {};

    for (int k0 = 0; k0 < K; k0 += BK) {
        // --- stage A (float4 coalesced) ---
        const float4 av = *(const float4*)(A + (size_t)(m0 + a_r) * K + k0 + a_k);
        As[a_r][a_k + 0] = av.x;
        As[a_r][a_k + 1] = av.y;
        As[a_r][a_k + 2] = av.z;
        As[a_r][a_k + 3] = av.w;
        // --- stage B ---
        if (!BT) {
            const int b_k = tid >> 4;            // 0..15
            const int b_n = (tid & 15) << 2;     // 0..60
            const int gn = n0 + b_n;
            if (gn + 3 < N) {
                const float4 bv = *(const float4*)(B + (size_t)(k0 + b_k) * N + gn);
                Bs[b_k][b_n + 0] = bv.x;
                Bs[b_k][b_n + 1] = bv.y;
                Bs[b_k][b_n + 2] = bv.z;
                Bs[b_k][b_n + 3] = bv.w;
            } else {
                #pragma unroll
                for (int j = 0; j < 4; ++j)
                    Bs[b_k][b_n + j] = (gn + j < N) ? B[(size_t)(k0 + b_k) * N + gn + j] : 0.f;
            }
        } else {
            const int b_n = tid >> 2;            // 0..63
            const int b_k = (tid & 3) << 2;      // 0,4,8,12
            const int gn = n0 + b_n;
            if (gn < N) {
                const float4 bv = *(const float4*)(B + (size_t)gn * K + k0 + b_k);
                Bs[b_k + 0][b_n] = bv.x;
                Bs[b_k + 1][b_n] = bv.y;
                Bs[b_k + 2][b_n] = bv.z;
                Bs[b_k + 3][b_n] = bv.w;
            } else {
                #pragma unroll
                for (int j = 0; j < 4; ++j) Bs[b_k + j][b_n] = 0.f;
            }
        }
        __syncthreads();

        #pragma unroll
        for (int kk = 0; kk < BK; ++kk) {
            float a[4], bb[4];
            #pragma unroll
            for (int i = 0; i < 4; ++i) a[i] = As[ty * 4 + i][kk];
            #pragma unroll
            for (int j = 0; j < 4; ++j) bb[j] = Bs[kk][tx * 4 + j];
            #pragma unroll
            for (int i = 0; i < 4; ++i)
                #pragma unroll
                for (int j = 0; j < 4; ++j)
                    acc[i][j] += a[i] * bb[j];
        }
        __syncthreads();
    }

    // --- epilogue ---
    #pragma unroll
    for (int i = 0; i < 4; ++i) {
        const int gm = m0 + ty * 4 + i;
        #pragma unroll
        for (int j = 0; j < 4; ++j) {
            const int gn = n0 + tx * 4 + j;
            if (gn < N) {
                float v = acc[i][j];
                if (bias) v += bias[gn];
                if (ACT == 1) v = fmap_f(v);
                if (ACT == 2) v = gelu_f(v);
                if (RES) v += Rsrc[(size_t)gm * N + gn];
                C[(size_t)gm * N + gn] = v;
            }
        }
    }
}

// ---------------- attention phase 1: per-chunk Mc = K^T V, ksum ----------------
__global__ __launch_bounds__(256) void attn_p1(
    const float* __restrict__ kbuf, const float* __restrict__ vbuf,
    float* __restrict__ Mc, float* __restrict__ ksum)
{
    const int h = blockIdx.x >> 5, c = blockIdx.x & 31;
    const int tid = threadIdx.x;
    const int tx = tid & 15, ty = tid >> 4;
    __shared__ float Ks[CHUNK][HD + 1];
    __shared__ float Vs[CHUNK][HD + 1];
    #pragma unroll
    for (int i = 0; i < 16; ++i) {
        int idx = tid + i * 256;           // 0..4095
        int t = idx >> 6, d = idx & 63;
        size_t g = (size_t)(c * CHUNK + t) * DIM + h * HD + d;
        Ks[t][d] = kbuf[g];
        Vs[t][d] = vbuf[g];
    }
    __syncthreads();

    float acc[4][4] = {};
    for (int t = 0; t < CHUNK; ++t) {
        float ka[4], vb[4];
        #pragma unroll
        for (int i = 0; i < 4; ++i) ka[i] = Ks[t][ty * 4 + i];
        #pragma unroll
        for (int j = 0; j < 4; ++j) vb[j] = Vs[t][tx * 4 + j];
        #pragma unroll
        for (int i = 0; i < 4; ++i)
            #pragma unroll
            for (int j = 0; j < 4; ++j)
                acc[i][j] += ka[i] * vb[j];
    }
    const size_t base = (size_t)(h * NCHUNK + c) * HD * HD;
    #pragma unroll
    for (int i = 0; i < 4; ++i)
        #pragma unroll
        for (int j = 0; j < 4; ++j)
            Mc[base + (size_t)(ty * 4 + i) * HD + tx * 4 + j] = acc[i][j];

    if (tid < HD) {
        float s = 0.f;
        for (int t = 0; t < CHUNK; ++t) s += Ks[t][tid];
        ksum[(size_t)(h * NCHUNK + c) * HD + tid] = s;
    }
}

// ---------------- attention phase 2: exclusive prefix over chunks ----------------
__global__ __launch_bounds__(64) void attn_scan(
    float* __restrict__ Mc, float* __restrict__ ksum)
{
    const int b = blockIdx.x;        // 0 .. 8*65-1
    const int h = b / 65, p = b % 65;
    const int tid = threadIdx.x;     // 0..63
    if (p < HD) {
        float run = 0.f;
        for (int c = 0; c < NCHUNK; ++c) {
            size_t idx = ((size_t)(h * NCHUNK + c) * HD + p) * HD + tid;
            float v = Mc[idx];
            Mc[idx] = run;
            run += v;
        }
    } else {
        float run = 0.f;
        for (int c = 0; c < NCHUNK; ++c) {
            size_t idx = (size_t)(h * NCHUNK + c) * HD + tid;
            float v = ksum[idx];
            ksum[idx] = run;
            run += v;
        }
    }
}

// ---------------- attention phase 3: intra-chunk + state, normalize ----------------
__global__ __launch_bounds__(256) void attn_p3(
    const float* __restrict__ qbuf, const float* __restrict__ kbuf,
    const float* __restrict__ vbuf, const float* __restrict__ Mc,
    const float* __restrict__ ksum, float* __restrict__ ao)
{
    const int h = blockIdx.x >> 5, c = blockIdx.x & 31;
    const int tid = threadIdx.x;
    const int tx = tid & 15, ty = tid >> 4;
    __shared__ float Qs[CHUNK][HD + 1];
    __shared__ float Ks[CHUNK][HD + 1];
    __shared__ float Vs[CHUNK][HD + 1];
    __shared__ float Ss[CHUNK][CHUNK + 1];
    __shared__ float Ms[HD][HD + 1];
    __shared__ float kp[HD], den[CHUNK];

    const size_t mbase = (size_t)(h * NCHUNK + c) * HD * HD;
    #pragma unroll
    for (int i = 0; i < 16; ++i) {
        int idx = tid + i * 256;
        int t = idx >> 6, d = idx & 63;
        size_t g = (size_t)(c * CHUNK + t) * DIM + h * HD + d;
        Qs[t][d] = qbuf[g];
        Ks[t][d] = kbuf[g];
        Vs[t][d] = vbuf[g];
        Ms[t][d] = Mc[mbase + (size_t)t * HD + d];
    }
    if (tid < HD) kp[tid] = ksum[(size_t)(h * NCHUNK + c) * HD + tid];
    __syncthreads();

    // S = Q K^T with causal mask (within chunk)
    {
        float acc[4][4] = {};
        for (int d = 0; d < HD; ++d) {
            float qa[4], kb[4];
            #pragma unroll
            for (int i = 0; i < 4; ++i) qa[i] = Qs[ty * 4 + i][d];
            #pragma unroll
            for (int j = 0; j < 4; ++j) kb[j] = Ks[tx * 4 + j][d];
            #pragma unroll
            for (int i = 0; i < 4; ++i)
                #pragma unroll
                for (int j = 0; j < 4; ++j)
                    acc[i][j] += qa[i] * kb[j];
        }
        #pragma unroll
        for (int i = 0; i < 4; ++i)
            #pragma unroll
            for (int j = 0; j < 4; ++j) {
                int t = ty * 4 + i, u = tx * 4 + j;
                Ss[t][u] = (u <= t) ? acc[i][j] : 0.f;
            }
    }
    __syncthreads();

    // den_t = 1e-6 + q_t . ksum_pre + rowsum(masked S)
    if (tid < CHUNK) {
        int t = tid;
        float s = 1e-6f;
        for (int d = 0; d < HD; ++d) s += Qs[t][d] * kp[d];
        for (int u = 0; u < CHUNK; ++u) s += Ss[t][u];
        den[t] = s;
    }
    __syncthreads();

    // out = (Q @ Mpre + S @ V) / den
    {
        float acc[4][4] = {};
        for (int d = 0; d < HD; ++d) {
            float qa[4], mb[4];
            #pragma unroll
            for (int i = 0; i < 4; ++i) qa[i] = Qs[ty * 4 + i][d];
            #pragma unroll
            for (int j = 0; j < 4; ++j) mb[j] = Ms[d][tx * 4 + j];
            #pragma unroll
            for (int i = 0; i < 4; ++i)
                #pragma unroll
                for (int j = 0; j < 4; ++j)
                    acc[i][j] += qa[i] * mb[j];
        }
        for (int u = 0; u < CHUNK; ++u) {
            float sa[4], vb[4];
            #pragma unroll
            for (int i = 0; i < 4; ++i) sa[i] = Ss[ty * 4 + i][u];
            #pragma unroll
            for (int j = 0; j < 4; ++j) vb[j] = Vs[u][tx * 4 + j];
            #pragma unroll
            for (int i = 0; i < 4; ++i)
                #pragma unroll
                for (int j = 0; j < 4; ++j)
                    acc[i][j] += sa[i] * vb[j];
        }
        #pragma unroll
        for (int i = 0; i < 4; ++i) {
            int t = ty * 4 + i;
            float inv = 1.f / den[t];
            #pragma unroll
            for (int j = 0; j < 4; ++j)
                ao[(size_t)(c * CHUNK + t) * DIM + h * HD + tx * 4 + j] = acc[i][j] * inv;
        }
    }
}

// ---------------- host launch ----------------
extern "C" void kernel_launch(void* const* d_in, const int* in_sizes, int n_in,
                              void* d_out, int out_size, void* d_ws, size_t ws_size,
                              hipStream_t stream)
{
    const float* tok  = (const float*)d_in[0];
    const float* pos  = (const float*)d_in[1];
    const float* ln1w = (const float*)d_in[2];
    const float* ln1b = (const float*)d_in[3];
    const float* wq   = (const float*)d_in[4];
    const float* wk   = (const float*)d_in[5];
    const float* wv   = (const float*)d_in[6];
    const float* wo   = (const float*)d_in[7];
    const float* ln2w = (const float*)d_in[8];
    const float* ln2b = (const float*)d_in[9];
    const float* w1   = (const float*)d_in[10];
    const float* b1   = (const float*)d_in[11];
    const float* w2   = (const float*)d_in[12];
    const float* b2   = (const float*)d_in[13];
    const float* lnfw = (const float*)d_in[14];
    const float* lnfb = (const float*)d_in[15];
    const int*   ids  = (const int*)d_in[16];
    float* outp = (float*)d_out;

    float* ws  = (float*)d_ws;
    float* x   = ws;                         // S*D
    float* xn  = x   + SD;                   // S*D
    float* q   = xn  + SD;                   // S*D (reused as CMS buf 0)
    float* k   = q   + SD;                   // S*D (reused as CMS buf 1)
    float* v   = k   + SD;                   // S*D
    float* ao  = v   + SD;                   // S*D
    float* h1  = ao  + SD;                   // S*HID
    float* Mc  = h1  + (size_t)SQL * HID;    // 8*32*64*64
    float* ksm = Mc  + (size_t)NHEADS * NCHUNK * HD * HD; // 8*32*64

    embed_k<<<SD / 256, 256, 0, stream>>>(tok, pos, ids, x);

    const dim3 g512(DIM / BN, SQL / BM);     // (8, 32)
    const dim3 ghid(HID / BN, SQL / BM);     // (32, 32)

    for (int l = 0; l < NLAYERS; ++l) {
        // --- attention block ---
        ln_k<<<SQL, 256, 0, stream>>>(x, xn, ln1w + l * DIM, ln1b + l * DIM);
        gemm_k<1, false, false><<<g512, 256, 0, stream>>>(
            xn, wq + (size_t)l * DIM * DIM, nullptr, nullptr, q, SQL, DIM, DIM);
        gemm_k<1, false, false><<<g512, 256, 0, stream>>>(
            xn, wk + (size_t)l * DIM * DIM, nullptr, nullptr, k, SQL, DIM, DIM);
        gemm_k<0, false, false><<<g512, 256, 0, stream>>>(
            xn, wv + (size_t)l * DIM * DIM, nullptr, nullptr, v, SQL, DIM, DIM);
        attn_p1<<<NHEADS * NCHUNK, 256, 0, stream>>>(k, v, Mc, ksm);
        attn_scan<<<NHEADS * 65, 64, 0, stream>>>(Mc, ksm);
        attn_p3<<<NHEADS * NCHUNK, 256, 0, stream>>>(q, k, v, Mc, ksm, ao);
        // x += ao @ wo
        gemm_k<0, false, true><<<g512, 256, 0, stream>>>(
            ao, wo + (size_t)l * DIM * DIM, nullptr, x, x, SQL, DIM, DIM);

        // --- CMS block ---
        ln_k<<<SQL, 256, 0, stream>>>(x, xn, ln2w + l * DIM, ln2b + l * DIM);
        const float* cin = xn;
        float* couts[2] = { q, k };          // q,k free after attention
        for (int lvl = 0; lvl < NLEVELS; ++lvl) {
            const float* w1p = w1 + (size_t)(l * NLEVELS + lvl) * DIM * HID;
            const float* b1p = b1 + (size_t)(l * NLEVELS + lvl) * HID;
            const float* w2p = w2 + (size_t)(l * NLEVELS + lvl) * HID * DIM;
            const float* b2p = b2 + (size_t)(l * NLEVELS + lvl) * DIM;
            gemm_k<2, false, false><<<ghid, 256, 0, stream>>>(
                cin, w1p, b1p, nullptr, h1, SQL, HID, DIM);
            if (lvl < NLEVELS - 1) {
                gemm_k<0, false, false><<<g512, 256, 0, stream>>>(
                    h1, w2p, b2p, nullptr, couts[lvl], SQL, DIM, HID);
                cin = couts[lvl];
            } else {
                // fuse residual: x += level_out
                gemm_k<0, false, true><<<g512, 256, 0, stream>>>(
                    h1, w2p, b2p, x, x, SQL, DIM, HID);
            }
        }
    }

    // --- final LN + tied head ---
    ln_k<<<SQL, 256, 0, stream>>>(x, xn, lnfw, lnfb);
    const dim3 ghead((VOC + BN - 1) / BN, SQL / BM);  // (786, 32)
    gemm_k<0, true, false><<<ghead, 256, 0, stream>>>(
        xn, tok, nullptr, nullptr, outp, SQL, VOC, DIM);
}